// Round 5
// baseline (2179.532 us; speedup 1.0000x reference)
//
#include <hip/hip_runtime.h>
#include <hip/hip_cooperative_groups.h>
#include <math.h>

namespace cg = cooperative_groups;

#define NLEN   32768
#define NATOMS 256
#define ATOM_S 512
#define NSTEPS 16
#define NCHAN  8   // 2 signals x 4 batches
#define NSEL   (NCHAN * NSTEPS)   // 128

// ---------- packed ordered key helpers ----------
__device__ __forceinline__ unsigned int ord32(float x) {
    unsigned int u = __float_as_uint(x);
    return (u & 0x80000000u) ? ~u : (u | 0x80000000u);
}
__device__ __forceinline__ float unord32(unsigned int o) {
    unsigned int u = (o & 0x80000000u) ? (o & 0x7FFFFFFFu) : ~o;
    return __uint_as_float(u);
}
// bigger key = bigger v, then smaller atom, then smaller position
__device__ __forceinline__ unsigned long long packkey(float v, int a, int q) {
    return ((unsigned long long)ord32(v) << 23)
         | ((unsigned long long)((255 - a) & 255) << 15)
         | (unsigned long long)((NLEN - 1 - q) & 32767);
}

// ---------- prep: normalize dict (transposed layout), init residual/keys ----------
__global__ void prep_kernel(const float* __restrict__ recon,
                            const float* __restrict__ target,
                            const float* __restrict__ d,
                            float* __restrict__ d_t,
                            float* __restrict__ residual,
                            unsigned long long* __restrict__ mkey,
                            unsigned long long* __restrict__ stepkey) {
    int b = blockIdx.x, t = threadIdx.x;
    if (b < NATOMS) {
        __shared__ float red[256];
        float x0 = d[b * ATOM_S + t];
        float x1 = d[b * ATOM_S + 256 + t];
        red[t] = x0 * x0 + x1 * x1;
        __syncthreads();
        for (int off = 128; off; off >>= 1) {
            if (t < off) red[t] += red[t + off];
            __syncthreads();
        }
        float denom = sqrtf(red[0]) + 1e-8f;
        int s0 = t, s1 = t + 256;
        d_t[((s0 >> 2) * NATOMS + b) * 4 + (s0 & 3)] = x0 / denom;
        d_t[((s1 >> 2) * NATOMS + b) * 4 + (s1 & 3)] = x1 / denom;
    } else if (b < NATOMS + 32) {
        int blk = b - NATOMS;
        for (int i = 0; i < 32; ++i) {
            int idx = blk * 8192 + i * 256 + t;     // 0 .. 262143
            int c = idx >> 15, q = idx & (NLEN - 1);
            residual[idx] = (c < 4) ? recon[c * NLEN + q] : target[(c - 4) * NLEN + q];
            mkey[idx] = 0ull;
        }
    } else {
        if (t < NSEL) stepkey[t] = 0ull;
    }
}

// ---------- 8-atom sliding-window dot: 128 FMAs per LDS float4 read ----------
__device__ __forceinline__ void dot8(const float* __restrict__ lres, int base,
                                     const float4* __restrict__ dt0,
                                     float acc[8][4]) {
#pragma unroll
    for (int aa = 0; aa < 8; ++aa)
#pragma unroll
        for (int j = 0; j < 4; ++j) acc[aa][j] = 0.0f;
    float4 rc = *(const float4*)&lres[base];
    const float4* dt = dt0;
#pragma unroll 1
    for (int s4 = 0; s4 < ATOM_S / 4; ++s4) {
        float4 rn = *(const float4*)&lres[base + s4 * 4 + 4];
#pragma unroll
        for (int aa = 0; aa < 8; ++aa) {
            float4 dv = dt[aa];
            acc[aa][0] = fmaf(rc.x, dv.x, acc[aa][0]);
            acc[aa][0] = fmaf(rc.y, dv.y, acc[aa][0]);
            acc[aa][0] = fmaf(rc.z, dv.z, acc[aa][0]);
            acc[aa][0] = fmaf(rc.w, dv.w, acc[aa][0]);
            acc[aa][1] = fmaf(rc.y, dv.x, acc[aa][1]);
            acc[aa][1] = fmaf(rc.z, dv.y, acc[aa][1]);
            acc[aa][1] = fmaf(rc.w, dv.z, acc[aa][1]);
            acc[aa][1] = fmaf(rn.x, dv.w, acc[aa][1]);
            acc[aa][2] = fmaf(rc.z, dv.x, acc[aa][2]);
            acc[aa][2] = fmaf(rc.w, dv.y, acc[aa][2]);
            acc[aa][2] = fmaf(rn.x, dv.z, acc[aa][2]);
            acc[aa][2] = fmaf(rn.y, dv.w, acc[aa][2]);
            acc[aa][3] = fmaf(rc.w, dv.x, acc[aa][3]);
            acc[aa][3] = fmaf(rn.x, dv.y, acc[aa][3]);
            acc[aa][3] = fmaf(rn.y, dv.z, acc[aa][3]);
            acc[aa][3] = fmaf(rn.z, dv.w, acc[aa][3]);
        }
        dt += NATOMS;
        rc = rn;
    }
}

// ---------- initial full correlation; per-position max + step-0 argmax ----------
// grid (32 tiles of 1024 pos, 8 channels, 8 atom-groups of 32), 256 threads
__global__ __launch_bounds__(256) void init_conv(const float* __restrict__ residual,
                                                 const float* __restrict__ d_t,
                                                 unsigned long long* __restrict__ mkey,
                                                 unsigned long long* __restrict__ stepkey) {
    __shared__ __align__(16) float lres[1536 + 16];
    __shared__ unsigned long long kred[256];
    int q0 = blockIdx.x * 1024;
    int c  = blockIdx.y;
    int ag = blockIdx.z;
    int t  = threadIdx.x;
    const float* res = residual + c * NLEN;
    for (int i = t; i < 1536; i += 256) {
        int g = q0 + i;
        lres[i] = (g < NLEN) ? res[g] : 0.0f;
    }
    __syncthreads();

    int base = t * 4;
    float bestv[4] = {-INFINITY, -INFINITY, -INFINITY, -INFINITY};
    int   besta[4] = {0, 0, 0, 0};
#pragma unroll 1
    for (int g8 = 0; g8 < 4; ++g8) {
        int a0 = ag * 32 + g8 * 8;
        float acc[8][4];
        dot8(lres, base, (const float4*)d_t + a0, acc);
#pragma unroll
        for (int aa = 0; aa < 8; ++aa)
#pragma unroll
            for (int j = 0; j < 4; ++j)
                if (acc[aa][j] > bestv[j]) { bestv[j] = acc[aa][j]; besta[j] = a0 + aa; }
    }
    unsigned long long* mk = mkey + c * NLEN;
    unsigned long long myk = 0ull;
#pragma unroll
    for (int j = 0; j < 4; ++j) {
        int q = q0 + base + j;
        unsigned long long k = packkey(bestv[j], besta[j], q);
        atomicMax(&mk[q], k);
        if (k > myk) myk = k;
    }
    kred[t] = myk;
    __syncthreads();
    for (int off = 128; off; off >>= 1) {
        if (t < off) { if (kred[t + off] > kred[t]) kred[t] = kred[t + off]; }
        __syncthreads();
    }
    if (t == 0) atomicMax(&stepkey[c], kred[0]);
}

// ---------- shared body: residual update + zero key window (one block per channel) ----------
__device__ __forceinline__ void finish_body(float* __restrict__ residual,
                                            const float* __restrict__ d_t,
                                            unsigned long long* __restrict__ mkey,
                                            const unsigned long long* __restrict__ stepkey,
                                            int k, int c, int t) {
    unsigned long long key = stepkey[k * NCHAN + c];
    int a = 255 - (int)((key >> 15) & 255);
    int p = (NLEN - 1) - (int)(key & 32767);
    float v = unord32((unsigned int)(key >> 23));
    float* resc = residual + c * NLEN;
    for (int i = t; i < ATOM_S; i += 256) {
        int q = p + i;
        if (q < NLEN) {
            float dval = d_t[((i >> 2) * NATOMS + a) * 4 + (i & 3)];
            resc[q] = __fsub_rn(resc[q], __fmul_rn(v, dval));
        }
    }
    int w0 = max(0, p - (ATOM_S - 1));
    int w1 = min(NLEN, p + ATOM_S);
    for (int q = w0 + t; q < w1; q += 256) mkey[c * NLEN + q] = 0ull;
}

// ---------- shared body: window recompute + outside scan -> stepkey[k+1] ----------
// b in [0,256): c = b>>5; r = b&31: tile = r>>3 (4 x 256 pos), ag = r&7 (8 x 32 atoms);
// plus outside-scan slice seg r (1024 positions)
__device__ __forceinline__ void window_scan_body(const float* __restrict__ residual,
                                                 const float* __restrict__ d_t,
                                                 unsigned long long* __restrict__ mkey,
                                                 unsigned long long* __restrict__ stepkey,
                                                 int k, int b, int t,
                                                 float* lres, unsigned long long* kred) {
    int c = b >> 5, r = b & 31;
    int tile = r >> 3, ag = r & 7;
    unsigned long long key = stepkey[k * NCHAN + c];
    int p = (NLEN - 1) - (int)(key & 32767);
    int w0 = max(0, p - (ATOM_S - 1));
    int w1 = min(NLEN, p + ATOM_S);
    int qstart = w0 + tile * 256;
    const float* res = residual + c * NLEN;
    for (int i = t; i < 768; i += 256) {
        int g = qstart + i;
        lres[i] = (g < NLEN) ? res[g] : 0.0f;
    }
    __syncthreads();

    int wv = t >> 6, l = t & 63;
    int base = l * 4;
    int a0 = ag * 32 + wv * 8;
    float acc[8][4];
    dot8(lres, base, (const float4*)d_t + a0, acc);

    float bestv[4] = {-INFINITY, -INFINITY, -INFINITY, -INFINITY};
    int   besta[4] = {0, 0, 0, 0};
#pragma unroll
    for (int aa = 0; aa < 8; ++aa)
#pragma unroll
        for (int j = 0; j < 4; ++j)
            if (acc[aa][j] > bestv[j]) { bestv[j] = acc[aa][j]; besta[j] = a0 + aa; }

    unsigned long long* mk = mkey + c * NLEN;
    unsigned long long myk = 0ull;
#pragma unroll
    for (int j = 0; j < 4; ++j) {
        int q = qstart + base + j;
        if (q < w1) {
            unsigned long long kk = packkey(bestv[j], besta[j], q);
            atomicMax(&mk[q], kk);
            if (kk > myk) myk = kk;
        }
    }
    // outside-window scan slice: 1024 positions at seg r
    {
        int q0 = r * 1024;
#pragma unroll
        for (int i = 0; i < 4; ++i) {
            int q = q0 + i * 256 + t;
            if (q < w0 || q >= w1) {
                unsigned long long kk = mk[q];
                if (kk > myk) myk = kk;
            }
        }
    }
    kred[t] = myk;
    __syncthreads();
    for (int off = 128; off; off >>= 1) {
        if (t < off) { if (kred[t + off] > kred[t]) kred[t] = kred[t + off]; }
        __syncthreads();
    }
    if (t == 0) atomicMax(&stepkey[(k + 1) * NCHAN + c], kred[0]);
    __syncthreads();
}

// ---------- shared body: loss from stepkey (call with 256 threads, one block) ----------
__device__ void loss_body(const unsigned long long* __restrict__ stepkey,
                          float* __restrict__ out, int t) {
    __shared__ int   lsa[NSEL], lsp[NSEL];
    __shared__ float lsv[NSEL];
    __shared__ double red[256];
    __shared__ double smx;

    if (t < NSEL) {
        int c = t >> 4, k = t & 15;            // sel index = c*NSTEPS + k
        unsigned long long key = stepkey[k * NCHAN + c];
        lsa[t] = 255 - (int)((key >> 15) & 255);
        lsp[t] = (NLEN - 1) - (int)(key & 32767);
        lsv[t] = unord32((unsigned int)(key >> 23));
    }
    __syncthreads();

    int myc = (t < NSEL) ? (t >> 4) : -1;
    int mya = (t < NSEL) ? lsa[t] : -1;
    int myp = (t < NSEL) ? lsp[t] : -1;

    // per-(c,a,p) dedup
    int fullowner = t;
    double fullsum = 0.0;
    if (t < NSEL) {
        for (int j = 0; j < NSEL; ++j) {
            if ((j >> 4) == myc && lsa[j] == mya && lsp[j] == myp) {
                if (j < fullowner) fullowner = j;
                fullsum += (double)lsv[j];
            }
        }
    }
    red[t] = (t < NSEL && fullowner == t) ? fullsum : 0.0;
    __syncthreads();
    for (int off = 128; off; off >>= 1) {
        if (t < off) red[t] = fmax(red[t], red[t + off]);
        __syncthreads();
    }
    if (t == 0) smx = red[0];
    __syncthreads();
    double mx = smx;

    // per-(b,a,p) group across r/t halves
    int gowner = t;
    double rv = 0.0, tv = 0.0;
    if (t < NSEL) {
        int myb = myc & 3;
        for (int j = 0; j < NSEL; ++j) {
            int jc = j >> 4;
            if ((jc & 3) == myb && lsa[j] == mya && lsp[j] == myp) {
                if (j < gowner) gowner = j;
                if (jc < 4) rv += (double)lsv[j]; else tv += (double)lsv[j];
            }
        }
    }

    const double EPS = 1e-12;
    double bg_term = -log1p(-EPS);

    double extra = 0.0;
    if (t < NSEL && gowner == t) {
        double r = rv / mx, tt = tv / mx;
        double rc = r;
        if (rc < EPS) rc = EPS;
        if (rc > 1.0) rc = 1.0;
        double lr = log(rc);  if (lr < -100.0) lr = -100.0;
        double l1 = (rc >= 1.0) ? -100.0 : log1p(-rc);
        if (l1 < -100.0) l1 = -100.0;
        double term = -(tt * lr + (1.0 - tt) * l1);
        extra = term - bg_term;
    }

    red[t] = extra;
    __syncthreads();
    for (int off = 128; off; off >>= 1) {
        if (t < off) red[t] += red[t + off];
        __syncthreads();
    }
    if (t == 0) {
        const double count = 33554432.0;  // 4 * 256 * 32768
        double total = count * bg_term + red[0];
        out[0] = (float)(total / count);
    }
}

// ---------- cooperative fused step loop (256 blocks = 1/CU) ----------
__global__ __launch_bounds__(256) void step_loop(float* __restrict__ residual,
                                                 const float* __restrict__ d_t,
                                                 unsigned long long* __restrict__ mkey,
                                                 unsigned long long* __restrict__ stepkey,
                                                 float* __restrict__ out) {
    cg::grid_group grid = cg::this_grid();
    int b = blockIdx.x, t = threadIdx.x;
    __shared__ __align__(16) float lres[768 + 16];
    __shared__ unsigned long long kred[256];

    for (int k = 0; k < NSTEPS - 1; ++k) {
        if (b < NCHAN) finish_body(residual, d_t, mkey, stepkey, k, b, t);
        grid.sync();
        window_scan_body(residual, d_t, mkey, stepkey, k, b, t, lres, kred);
        grid.sync();
    }
    if (b == 0) loss_body(stepkey, out, t);
}

// ---------- fallback kernels (used if cooperative launch is rejected) ----------
__global__ void finish_step(float* __restrict__ residual,
                            const float* __restrict__ d_t,
                            unsigned long long* __restrict__ mkey,
                            const unsigned long long* __restrict__ stepkey, int k) {
    finish_body(residual, d_t, mkey, stepkey, k, blockIdx.x, threadIdx.x);
}

__global__ __launch_bounds__(256) void window_scan(const float* __restrict__ residual,
                                                   const float* __restrict__ d_t,
                                                   unsigned long long* __restrict__ mkey,
                                                   unsigned long long* __restrict__ stepkey,
                                                   int k) {
    __shared__ __align__(16) float lres[768 + 16];
    __shared__ unsigned long long kred[256];
    window_scan_body(residual, d_t, mkey, stepkey, k, blockIdx.x, threadIdx.x, lres, kred);
}

__global__ __launch_bounds__(256) void loss_kernel(const unsigned long long* __restrict__ stepkey,
                                                   float* __restrict__ out) {
    loss_body(stepkey, out, threadIdx.x);
}

// ---------- launch ----------
extern "C" void kernel_launch(void* const* d_in, const int* in_sizes, int n_in,
                              void* d_out, int out_size, void* d_ws, size_t ws_size,
                              hipStream_t stream) {
    const float* recon  = (const float*)d_in[0];
    const float* target = (const float*)d_in[1];
    const float* d      = (const float*)d_in[2];
    char* ws = (char*)d_ws;
    float* d_t                    = (float*)(ws);                        // 524288 B
    float* residual               = (float*)(ws + 524288);               // 1048576 B
    unsigned long long* mkey      = (unsigned long long*)(ws + 1572864); // 2097152 B
    unsigned long long* stepkey   = (unsigned long long*)(ws + 3670016); // 1024 B
    float* out = (float*)d_out;

    hipLaunchKernelGGL(prep_kernel, dim3(NATOMS + 33), dim3(256), 0, stream,
                       recon, target, d, d_t, residual, mkey, stepkey);
    hipLaunchKernelGGL(init_conv, dim3(32, NCHAN, 8), dim3(256), 0, stream,
                       residual, d_t, mkey, stepkey);

    void* args[] = { (void*)&residual, (void*)&d_t, (void*)&mkey,
                     (void*)&stepkey, (void*)&out };
    hipError_t e = hipLaunchCooperativeKernel((void*)step_loop, dim3(256), dim3(256),
                                              args, 0, stream);
    if (e != hipSuccess) {
        // fallback: same bodies, stream-ordered kernels
        for (int k = 0; k < NSTEPS - 1; ++k) {
            hipLaunchKernelGGL(finish_step, dim3(NCHAN), dim3(256), 0, stream,
                               residual, d_t, mkey, stepkey, k);
            hipLaunchKernelGGL(window_scan, dim3(256), dim3(256), 0, stream,
                               residual, d_t, mkey, stepkey, k);
        }
        hipLaunchKernelGGL(loss_kernel, dim3(1), dim3(256), 0, stream,
                           stepkey, out);
    }
}

// Round 6
// 1977.882 us; speedup vs baseline: 1.1020x; 1.1020x over previous
//
#include <hip/hip_runtime.h>
#include <math.h>

#define NLEN   32768
#define NATOMS 256
#define ATOM_S 512
#define NSTEPS 16
#define NCHAN  8   // 2 signals x 4 batches
#define NSEL   (NCHAN * NSTEPS)   // 128

// ---------- packed ordered key helpers ----------
__device__ __forceinline__ unsigned int ord32(float x) {
    unsigned int u = __float_as_uint(x);
    return (u & 0x80000000u) ? ~u : (u | 0x80000000u);
}
__device__ __forceinline__ float unord32(unsigned int o) {
    unsigned int u = (o & 0x80000000u) ? (o & 0x7FFFFFFFu) : ~o;
    return __uint_as_float(u);
}
// bigger key = bigger v, then smaller atom, then smaller position
__device__ __forceinline__ unsigned long long packkey(float v, int a, int q) {
    return ((unsigned long long)ord32(v) << 23)
         | ((unsigned long long)((255 - a) & 255) << 15)
         | (unsigned long long)((NLEN - 1 - q) & 32767);
}

// ---------- prep: normalize dict (transposed), init BOTH residual buffers ----------
__global__ void prep_kernel(const float* __restrict__ recon,
                            const float* __restrict__ target,
                            const float* __restrict__ d,
                            float* __restrict__ d_t,
                            float* __restrict__ res0,
                            float* __restrict__ res1,
                            unsigned long long* __restrict__ mkey,
                            unsigned long long* __restrict__ stepkey) {
    int b = blockIdx.x, t = threadIdx.x;
    if (b < NATOMS) {
        __shared__ float red[256];
        float x0 = d[b * ATOM_S + t];
        float x1 = d[b * ATOM_S + 256 + t];
        red[t] = x0 * x0 + x1 * x1;
        __syncthreads();
        for (int off = 128; off; off >>= 1) {
            if (t < off) red[t] += red[t + off];
            __syncthreads();
        }
        float denom = sqrtf(red[0]) + 1e-8f;
        int s0 = t, s1 = t + 256;
        d_t[((s0 >> 2) * NATOMS + b) * 4 + (s0 & 3)] = x0 / denom;
        d_t[((s1 >> 2) * NATOMS + b) * 4 + (s1 & 3)] = x1 / denom;
    } else if (b < NATOMS + 32) {
        int blk = b - NATOMS;
        for (int i = 0; i < 32; ++i) {
            int idx = blk * 8192 + i * 256 + t;     // 0 .. 262143
            int c = idx >> 15, q = idx & (NLEN - 1);
            float x = (c < 4) ? recon[c * NLEN + q] : target[(c - 4) * NLEN + q];
            res0[idx] = x;
            res1[idx] = x;
            mkey[idx] = 0ull;
        }
    } else {
        if (t < NSEL) stepkey[t] = 0ull;
    }
}

// ---------- 8-atom sliding-window dot: 128 FMAs per LDS float4 read ----------
__device__ __forceinline__ void dot8(const float* __restrict__ lres, int base,
                                     const float4* __restrict__ dt0,
                                     float acc[8][4]) {
#pragma unroll
    for (int aa = 0; aa < 8; ++aa)
#pragma unroll
        for (int j = 0; j < 4; ++j) acc[aa][j] = 0.0f;
    float4 rc = *(const float4*)&lres[base];
    const float4* dt = dt0;
#pragma unroll 1
    for (int s4 = 0; s4 < ATOM_S / 4; ++s4) {
        float4 rn = *(const float4*)&lres[base + s4 * 4 + 4];
#pragma unroll
        for (int aa = 0; aa < 8; ++aa) {
            float4 dv = dt[aa];
            acc[aa][0] = fmaf(rc.x, dv.x, acc[aa][0]);
            acc[aa][0] = fmaf(rc.y, dv.y, acc[aa][0]);
            acc[aa][0] = fmaf(rc.z, dv.z, acc[aa][0]);
            acc[aa][0] = fmaf(rc.w, dv.w, acc[aa][0]);
            acc[aa][1] = fmaf(rc.y, dv.x, acc[aa][1]);
            acc[aa][1] = fmaf(rc.z, dv.y, acc[aa][1]);
            acc[aa][1] = fmaf(rc.w, dv.z, acc[aa][1]);
            acc[aa][1] = fmaf(rn.x, dv.w, acc[aa][1]);
            acc[aa][2] = fmaf(rc.z, dv.x, acc[aa][2]);
            acc[aa][2] = fmaf(rc.w, dv.y, acc[aa][2]);
            acc[aa][2] = fmaf(rn.x, dv.z, acc[aa][2]);
            acc[aa][2] = fmaf(rn.y, dv.w, acc[aa][2]);
            acc[aa][3] = fmaf(rc.w, dv.x, acc[aa][3]);
            acc[aa][3] = fmaf(rn.x, dv.y, acc[aa][3]);
            acc[aa][3] = fmaf(rn.y, dv.z, acc[aa][3]);
            acc[aa][3] = fmaf(rn.z, dv.w, acc[aa][3]);
        }
        dt += NATOMS;
        rc = rn;
    }
}

// ---------- initial full correlation; per-position max + step-0 argmax ----------
// grid (32 tiles of 1024 pos, 8 channels, 8 atom-groups of 32), 256 threads
__global__ __launch_bounds__(256) void init_conv(const float* __restrict__ residual,
                                                 const float* __restrict__ d_t,
                                                 unsigned long long* __restrict__ mkey,
                                                 unsigned long long* __restrict__ stepkey) {
    __shared__ __align__(16) float lres[1536 + 16];
    __shared__ unsigned long long kred[256];
    int q0 = blockIdx.x * 1024;
    int c  = blockIdx.y;
    int ag = blockIdx.z;
    int t  = threadIdx.x;
    const float* res = residual + c * NLEN;
    for (int i = t; i < 1536; i += 256) {
        int g = q0 + i;
        lres[i] = (g < NLEN) ? res[g] : 0.0f;
    }
    __syncthreads();

    int base = t * 4;
    float bestv[4] = {-INFINITY, -INFINITY, -INFINITY, -INFINITY};
    int   besta[4] = {0, 0, 0, 0};
#pragma unroll 1
    for (int g8 = 0; g8 < 4; ++g8) {
        int a0 = ag * 32 + g8 * 8;
        float acc[8][4];
        dot8(lres, base, (const float4*)d_t + a0, acc);
#pragma unroll
        for (int aa = 0; aa < 8; ++aa)
#pragma unroll
            for (int j = 0; j < 4; ++j)
                if (acc[aa][j] > bestv[j]) { bestv[j] = acc[aa][j]; besta[j] = a0 + aa; }
    }
    unsigned long long* mk = mkey + c * NLEN;
    unsigned long long myk = 0ull;
#pragma unroll
    for (int j = 0; j < 4; ++j) {
        int q = q0 + base + j;
        unsigned long long k = packkey(bestv[j], besta[j], q);
        atomicMax(&mk[q], k);
        if (k > myk) myk = k;
    }
    kred[t] = myk;
    __syncthreads();
    for (int off = 128; off; off >>= 1) {
        if (t < off) { if (kred[t + off] > kred[t]) kred[t] = kred[t + off]; }
        __syncthreads();
    }
    if (t == 0) atomicMax(&stepkey[c], kred[0]);
}

// ---------- per-step kernel: 256 blocks, no device-wide sync needed ----------
// blocks 0..127  : window blocks (c = b>>4, tile = b&15): own 64 positions x 256 atoms,
//                  stage residual from buf_cur + apply delta_k in LDS, exclusive mkey store
// blocks 128..255: scan blocks (c, seg of 2048 pos) outside [w0,w1);
//                  the 8 with seg==0 also update buf_next with delta_{k-1}, delta_k
__global__ __launch_bounds__(256) void step_kernel(const float* __restrict__ buf_cur,
                                                   float* __restrict__ buf_next,
                                                   const float* __restrict__ d_t,
                                                   unsigned long long* __restrict__ mkey,
                                                   unsigned long long* __restrict__ stepkey,
                                                   int k) {
    int b = blockIdx.x, t = threadIdx.x;
    __shared__ __align__(16) float lres[576 + 16];
    __shared__ unsigned long long kk[16 * 65];
    __shared__ unsigned long long kred[256];

    if (b < 128) {
        int c = b >> 4, tile = b & 15;
        unsigned long long key = stepkey[k * NCHAN + c];
        int a = 255 - (int)((key >> 15) & 255);
        int p = (NLEN - 1) - (int)(key & 32767);
        float v = unord32((unsigned int)(key >> 23));
        int w0 = max(0, p - (ATOM_S - 1));
        int w1 = min(NLEN, p + ATOM_S);
        int qstart = w0 + tile * 64;
        const float* rc_ = buf_cur + c * NLEN;
        for (int i = t; i < 576; i += 256) {
            int g = qstart + i;
            float x = (g < NLEN) ? rc_[g] : 0.0f;
            int s = g - p;
            if (s >= 0 && s < ATOM_S && g < NLEN) {
                float dval = d_t[((s >> 2) * NATOMS + a) * 4 + (s & 3)];
                x = __fsub_rn(x, __fmul_rn(v, dval));
            }
            lres[i] = x;
        }
        __syncthreads();

        int sg = t >> 4, pg = t & 15;
        int base = pg * 4;
        float bestv[4] = {-INFINITY, -INFINITY, -INFINITY, -INFINITY};
        int   besta[4] = {0, 0, 0, 0};
#pragma unroll 1
        for (int g8 = 0; g8 < 2; ++g8) {
            int a0 = sg * 16 + g8 * 8;
            float acc[8][4];
            dot8(lres, base, (const float4*)d_t + a0, acc);
#pragma unroll
            for (int aa = 0; aa < 8; ++aa)
#pragma unroll
                for (int j = 0; j < 4; ++j)
                    if (acc[aa][j] > bestv[j]) { bestv[j] = acc[aa][j]; besta[j] = a0 + aa; }
        }
#pragma unroll
        for (int j = 0; j < 4; ++j)
            kk[sg * 65 + base + j] = packkey(bestv[j], besta[j], qstart + base + j);
        __syncthreads();
        for (int off = 8; off; off >>= 1) {
            if (sg < off) {
#pragma unroll
                for (int j = 0; j < 4; ++j) {
                    unsigned long long o = kk[(sg + off) * 65 + base + j];
                    if (o > kk[sg * 65 + base + j]) kk[sg * 65 + base + j] = o;
                }
            }
            __syncthreads();
        }
        unsigned long long myk = 0ull;
        if (sg == 0) {
            unsigned long long* mk = mkey + c * NLEN;
#pragma unroll
            for (int j = 0; j < 4; ++j) {
                int q = qstart + base + j;
                if (q < w1) {
                    unsigned long long kkey = kk[base + j];
                    mk[q] = kkey;              // exclusive owner: plain store
                    if (kkey > myk) myk = kkey;
                }
            }
        }
        kred[t] = myk;
        __syncthreads();
        for (int off = 128; off; off >>= 1) {
            if (t < off) { if (kred[t + off] > kred[t]) kred[t] = kred[t + off]; }
            __syncthreads();
        }
        if (t == 0) atomicMax(&stepkey[(k + 1) * NCHAN + c], kred[0]);
    } else {
        int sb = b - 128;
        int c = sb >> 4, seg = sb & 15;

        // writer duty: bring buf_next from R_{k-1} to R_{k+1} (sequential deltas)
        if (seg == 0) {
            float* bn = buf_next + c * NLEN;
            int s0 = (k > 0) ? (k - 1) : k;
            for (int s = s0; s <= k; ++s) {
                unsigned long long key = stepkey[s * NCHAN + c];
                int a = 255 - (int)((key >> 15) & 255);
                int p = (NLEN - 1) - (int)(key & 32767);
                float v = unord32((unsigned int)(key >> 23));
                for (int i = t; i < ATOM_S; i += 256) {
                    int q = p + i;
                    if (q < NLEN) {
                        float dval = d_t[((i >> 2) * NATOMS + a) * 4 + (i & 3)];
                        bn[q] = __fsub_rn(bn[q], __fmul_rn(v, dval));
                    }
                }
                __syncthreads();
            }
        }

        // scan duty: max over mkey outside [w0,w1)
        unsigned long long key = stepkey[k * NCHAN + c];
        int p = (NLEN - 1) - (int)(key & 32767);
        int w0 = max(0, p - (ATOM_S - 1));
        int w1 = min(NLEN, p + ATOM_S);
        const unsigned long long* mk = mkey + c * NLEN;
        unsigned long long myk = 0ull;
        int q0 = seg * 2048;
#pragma unroll
        for (int i = 0; i < 8; ++i) {
            int q = q0 + i * 256 + t;
            if (q < w0 || q >= w1) {
                unsigned long long kk2 = mk[q];
                if (kk2 > myk) myk = kk2;
            }
        }
        kred[t] = myk;
        __syncthreads();
        for (int off = 128; off; off >>= 1) {
            if (t < off) { if (kred[t + off] > kred[t]) kred[t] = kred[t + off]; }
            __syncthreads();
        }
        if (t == 0) atomicMax(&stepkey[(k + 1) * NCHAN + c], kred[0]);
    }
}

// ---------- final loss from stepkey (one block, 256 threads) ----------
__global__ __launch_bounds__(256) void loss_kernel(const unsigned long long* __restrict__ stepkey,
                                                   float* __restrict__ out) {
    int t = threadIdx.x;
    __shared__ int   lsa[NSEL], lsp[NSEL];
    __shared__ float lsv[NSEL];
    __shared__ double red[256];
    __shared__ double smx;

    if (t < NSEL) {
        int c = t >> 4, k = t & 15;            // sel index = c*NSTEPS + k
        unsigned long long key = stepkey[k * NCHAN + c];
        lsa[t] = 255 - (int)((key >> 15) & 255);
        lsp[t] = (NLEN - 1) - (int)(key & 32767);
        lsv[t] = unord32((unsigned int)(key >> 23));
    }
    __syncthreads();

    int myc = (t < NSEL) ? (t >> 4) : -1;
    int mya = (t < NSEL) ? lsa[t] : -1;
    int myp = (t < NSEL) ? lsp[t] : -1;

    // per-(c,a,p) dedup
    int fullowner = t;
    double fullsum = 0.0;
    if (t < NSEL) {
        for (int j = 0; j < NSEL; ++j) {
            if ((j >> 4) == myc && lsa[j] == mya && lsp[j] == myp) {
                if (j < fullowner) fullowner = j;
                fullsum += (double)lsv[j];
            }
        }
    }
    red[t] = (t < NSEL && fullowner == t) ? fullsum : 0.0;
    __syncthreads();
    for (int off = 128; off; off >>= 1) {
        if (t < off) red[t] = fmax(red[t], red[t + off]);
        __syncthreads();
    }
    if (t == 0) smx = red[0];
    __syncthreads();
    double mx = smx;

    // per-(b,a,p) group across r/t halves
    int gowner = t;
    double rv = 0.0, tv = 0.0;
    if (t < NSEL) {
        int myb = myc & 3;
        for (int j = 0; j < NSEL; ++j) {
            int jc = j >> 4;
            if ((jc & 3) == myb && lsa[j] == mya && lsp[j] == myp) {
                if (j < gowner) gowner = j;
                if (jc < 4) rv += (double)lsv[j]; else tv += (double)lsv[j];
            }
        }
    }

    const double EPS = 1e-12;
    double bg_term = -log1p(-EPS);

    double extra = 0.0;
    if (t < NSEL && gowner == t) {
        double r = rv / mx, tt = tv / mx;
        double rc = r;
        if (rc < EPS) rc = EPS;
        if (rc > 1.0) rc = 1.0;
        double lr = log(rc);  if (lr < -100.0) lr = -100.0;
        double l1 = (rc >= 1.0) ? -100.0 : log1p(-rc);
        if (l1 < -100.0) l1 = -100.0;
        double term = -(tt * lr + (1.0 - tt) * l1);
        extra = term - bg_term;
    }

    red[t] = extra;
    __syncthreads();
    for (int off = 128; off; off >>= 1) {
        if (t < off) red[t] += red[t + off];
        __syncthreads();
    }
    if (t == 0) {
        const double count = 33554432.0;  // 4 * 256 * 32768
        double total = count * bg_term + red[0];
        out[0] = (float)(total / count);
    }
}

// ---------- launch ----------
extern "C" void kernel_launch(void* const* d_in, const int* in_sizes, int n_in,
                              void* d_out, int out_size, void* d_ws, size_t ws_size,
                              hipStream_t stream) {
    const float* recon  = (const float*)d_in[0];
    const float* target = (const float*)d_in[1];
    const float* d      = (const float*)d_in[2];
    char* ws = (char*)d_ws;
    float* d_t                    = (float*)(ws);                        // 512 KB
    float* res0                   = (float*)(ws + 524288);               // 1 MB
    float* res1                   = (float*)(ws + 1572864);              // 1 MB
    unsigned long long* mkey      = (unsigned long long*)(ws + 2621440); // 2 MB
    unsigned long long* stepkey   = (unsigned long long*)(ws + 4718592); // 1 KB
    float* out = (float*)d_out;

    hipLaunchKernelGGL(prep_kernel, dim3(NATOMS + 33), dim3(256), 0, stream,
                       recon, target, d, d_t, res0, res1, mkey, stepkey);
    hipLaunchKernelGGL(init_conv, dim3(32, NCHAN, 8), dim3(256), 0, stream,
                       res0, d_t, mkey, stepkey);
    for (int k = 0; k < NSTEPS - 1; ++k) {
        float* cur  = (k & 1) ? res1 : res0;
        float* next = (k & 1) ? res0 : res1;
        hipLaunchKernelGGL(step_kernel, dim3(256), dim3(256), 0, stream,
                           cur, next, d_t, mkey, stepkey, k);
    }
    hipLaunchKernelGGL(loss_kernel, dim3(1), dim3(256), 0, stream,
                       stepkey, out);
}

// Round 7
// 1312.967 us; speedup vs baseline: 1.6600x; 1.5064x over previous
//
#include <hip/hip_runtime.h>
#include <math.h>

#define NLEN   32768
#define NATOMS 256
#define ATOM_S 512
#define NSTEPS 16
#define NCHAN  8   // 2 signals x 4 batches
#define NSEL   (NCHAN * NSTEPS)   // 128

// ---------- packed ordered key helpers ----------
__device__ __forceinline__ unsigned int ord32(float x) {
    unsigned int u = __float_as_uint(x);
    return (u & 0x80000000u) ? ~u : (u | 0x80000000u);
}
__device__ __forceinline__ float unord32(unsigned int o) {
    unsigned int u = (o & 0x80000000u) ? (o & 0x7FFFFFFFu) : ~o;
    return __uint_as_float(u);
}
// bigger key = bigger v, then smaller atom, then smaller position
__device__ __forceinline__ unsigned long long packkey(float v, int a, int q) {
    return ((unsigned long long)ord32(v) << 23)
         | ((unsigned long long)((255 - a) & 255) << 15)
         | (unsigned long long)((NLEN - 1 - q) & 32767);
}

// ---------- prep: normalize dict (transposed), init BOTH residual buffers ----------
__global__ void prep_kernel(const float* __restrict__ recon,
                            const float* __restrict__ target,
                            const float* __restrict__ d,
                            float* __restrict__ d_t,
                            float* __restrict__ res0,
                            float* __restrict__ res1,
                            unsigned long long* __restrict__ mkey,
                            unsigned long long* __restrict__ stepkey) {
    int b = blockIdx.x, t = threadIdx.x;
    if (b < NATOMS) {
        __shared__ float red[256];
        float x0 = d[b * ATOM_S + t];
        float x1 = d[b * ATOM_S + 256 + t];
        red[t] = x0 * x0 + x1 * x1;
        __syncthreads();
        for (int off = 128; off; off >>= 1) {
            if (t < off) red[t] += red[t + off];
            __syncthreads();
        }
        float denom = sqrtf(red[0]) + 1e-8f;
        int s0 = t, s1 = t + 256;
        d_t[((s0 >> 2) * NATOMS + b) * 4 + (s0 & 3)] = x0 / denom;
        d_t[((s1 >> 2) * NATOMS + b) * 4 + (s1 & 3)] = x1 / denom;
    } else if (b < NATOMS + 32) {
        int blk = b - NATOMS;
        for (int i = 0; i < 32; ++i) {
            int idx = blk * 8192 + i * 256 + t;     // 0 .. 262143
            int c = idx >> 15, q = idx & (NLEN - 1);
            float x = (c < 4) ? recon[c * NLEN + q] : target[(c - 4) * NLEN + q];
            res0[idx] = x;
            res1[idx] = x;
            mkey[idx] = 0ull;
        }
    } else {
        if (t < NSEL) stepkey[t] = 0ull;
    }
}

// ---------- 16 FMAs for one atom x 4 sliding positions (fixed order) ----------
__device__ __forceinline__ void fma16(float acc[4], float4 dv,
                                      const float4& rc, const float4& rn) {
    acc[0] = fmaf(rc.x, dv.x, acc[0]); acc[0] = fmaf(rc.y, dv.y, acc[0]);
    acc[0] = fmaf(rc.z, dv.z, acc[0]); acc[0] = fmaf(rc.w, dv.w, acc[0]);
    acc[1] = fmaf(rc.y, dv.x, acc[1]); acc[1] = fmaf(rc.z, dv.y, acc[1]);
    acc[1] = fmaf(rc.w, dv.z, acc[1]); acc[1] = fmaf(rn.x, dv.w, acc[1]);
    acc[2] = fmaf(rc.z, dv.x, acc[2]); acc[2] = fmaf(rc.w, dv.y, acc[2]);
    acc[2] = fmaf(rn.x, dv.z, acc[2]); acc[2] = fmaf(rn.y, dv.w, acc[2]);
    acc[3] = fmaf(rc.w, dv.x, acc[3]); acc[3] = fmaf(rn.x, dv.y, acc[3]);
    acc[3] = fmaf(rn.y, dv.z, acc[3]); acc[3] = fmaf(rn.z, dv.w, acc[3]);
}

// ---------- 8-atom sliding-window dot (TLP version, low VGPR: used by init) ----------
__device__ __forceinline__ void dot8(const float* __restrict__ lres, int base,
                                     const float4* __restrict__ dt0,
                                     float acc[8][4]) {
#pragma unroll
    for (int aa = 0; aa < 8; ++aa)
#pragma unroll
        for (int j = 0; j < 4; ++j) acc[aa][j] = 0.0f;
    float4 rc = *(const float4*)&lres[base];
    const float4* dt = dt0;
#pragma unroll 1
    for (int s4 = 0; s4 < ATOM_S / 4; ++s4) {
        float4 rn = *(const float4*)&lres[base + s4 * 4 + 4];
#pragma unroll
        for (int aa = 0; aa < 8; ++aa) fma16(acc[aa], dt[aa], rc, rn);
        dt += NATOMS;
        rc = rn;
    }
}

// ---------- 8-atom dot with 2-deep d_t register prefetch (ILP version: steps) ----------
// Same FMA order per (atom, position) as dot8 -> bit-identical results.
// NOTE: prefetches one row past d_t's end on the last iteration (lands in res0,
// in-bounds of the workspace, values never used).
__device__ __forceinline__ void dot8p(const float* __restrict__ lres, int base,
                                      const float4* __restrict__ dt0,
                                      float acc[8][4]) {
#pragma unroll
    for (int aa = 0; aa < 8; ++aa)
#pragma unroll
        for (int j = 0; j < 4; ++j) acc[aa][j] = 0.0f;
    float4 dva[8], dvb[8];
#pragma unroll
    for (int aa = 0; aa < 8; ++aa) dva[aa] = dt0[aa];
    float4 rc = *(const float4*)&lres[base];
    const float4* dtp = dt0;
#pragma unroll 1
    for (int s4 = 0; s4 < ATOM_S / 4; s4 += 2) {
        float4 rn = *(const float4*)&lres[base + s4 * 4 + 4];
#pragma unroll
        for (int aa = 0; aa < 8; ++aa) dvb[aa] = dtp[NATOMS + aa];
#pragma unroll
        for (int aa = 0; aa < 8; ++aa) fma16(acc[aa], dva[aa], rc, rn);
        float4 rn2 = *(const float4*)&lres[base + s4 * 4 + 8];
#pragma unroll
        for (int aa = 0; aa < 8; ++aa) dva[aa] = dtp[2 * NATOMS + aa];
#pragma unroll
        for (int aa = 0; aa < 8; ++aa) fma16(acc[aa], dvb[aa], rn, rn2);
        dtp += 2 * NATOMS;
        rc = rn2;
    }
}

// ---------- initial full correlation; per-position max + step-0 argmax ----------
// grid (32 tiles of 1024 pos, 8 channels, 8 atom-groups of 32), 256 threads
__global__ __launch_bounds__(256) void init_conv(const float* __restrict__ residual,
                                                 const float* __restrict__ d_t,
                                                 unsigned long long* __restrict__ mkey,
                                                 unsigned long long* __restrict__ stepkey) {
    __shared__ __align__(16) float lres[1536 + 16];
    __shared__ unsigned long long kred[256];
    int q0 = blockIdx.x * 1024;
    int c  = blockIdx.y;
    int ag = blockIdx.z;
    int t  = threadIdx.x;
    const float* res = residual + c * NLEN;
    for (int i = t; i < 1536; i += 256) {
        int g = q0 + i;
        lres[i] = (g < NLEN) ? res[g] : 0.0f;
    }
    __syncthreads();

    int base = t * 4;
    float bestv[4] = {-INFINITY, -INFINITY, -INFINITY, -INFINITY};
    int   besta[4] = {0, 0, 0, 0};
#pragma unroll 1
    for (int g8 = 0; g8 < 4; ++g8) {
        int a0 = ag * 32 + g8 * 8;
        float acc[8][4];
        dot8(lres, base, (const float4*)d_t + a0, acc);
#pragma unroll
        for (int aa = 0; aa < 8; ++aa)
#pragma unroll
            for (int j = 0; j < 4; ++j)
                if (acc[aa][j] > bestv[j]) { bestv[j] = acc[aa][j]; besta[j] = a0 + aa; }
    }
    unsigned long long* mk = mkey + c * NLEN;
    unsigned long long myk = 0ull;
#pragma unroll
    for (int j = 0; j < 4; ++j) {
        int q = q0 + base + j;
        unsigned long long k = packkey(bestv[j], besta[j], q);
        atomicMax(&mk[q], k);
        if (k > myk) myk = k;
    }
    kred[t] = myk;
    __syncthreads();
    for (int off = 128; off; off >>= 1) {
        if (t < off) { if (kred[t + off] > kred[t]) kred[t] = kred[t + off]; }
        __syncthreads();
    }
    if (t == 0) atomicMax(&stepkey[c], kred[0]);
}

// ---------- per-step kernel: 256 blocks x 256 threads, all CUs do window FMAs ----------
// block b: c = b>>5, r = b&31.
//   window duty : own 32 positions [w0+32r, w0+32r+32) x ALL 256 atoms; stage
//                 residual from buf_cur + delta_k on the fly; exclusive mkey store.
//   scan duty   : 1024-position slice r of mkey outside [w0,w1).
//   writer duty : r==0 blocks advance buf_next from R_{k-1} to R_{k+1}.
// All feed stepkey[k+1] via one atomicMax per block.
__global__ __launch_bounds__(256) void step_kernel(const float* __restrict__ buf_cur,
                                                   float* __restrict__ buf_next,
                                                   const float* __restrict__ d_t,
                                                   unsigned long long* __restrict__ mkey,
                                                   unsigned long long* __restrict__ stepkey,
                                                   int k) {
    int b = blockIdx.x, t = threadIdx.x;
    int c = b >> 5, r = b & 31;
    __shared__ __align__(16) float lres[544 + 16];
    __shared__ unsigned long long kk[32 * 33];
    __shared__ unsigned long long kred[256];

    unsigned long long key = stepkey[k * NCHAN + c];
    int a = 255 - (int)((key >> 15) & 255);
    int p = (NLEN - 1) - (int)(key & 32767);
    float v = unord32((unsigned int)(key >> 23));
    int w0 = max(0, p - (ATOM_S - 1));
    int w1 = min(NLEN, p + ATOM_S);
    int qstart = w0 + r * 32;

    // ---- writer duty (r==0): sequential deltas, bitwise = reference order ----
    if (r == 0) {
        float* bn = buf_next + c * NLEN;
        int s0 = (k > 0) ? (k - 1) : 0;
        for (int s = s0; s <= k; ++s) {
            unsigned long long ks = stepkey[s * NCHAN + c];
            int as = 255 - (int)((ks >> 15) & 255);
            int ps = (NLEN - 1) - (int)(ks & 32767);
            float vs = unord32((unsigned int)(ks >> 23));
            for (int i = t; i < ATOM_S; i += 256) {
                int q = ps + i;
                if (q < NLEN) {
                    float dval = d_t[((i >> 2) * NATOMS + as) * 4 + (i & 3)];
                    bn[q] = __fsub_rn(bn[q], __fmul_rn(vs, dval));
                }
            }
            __syncthreads();   // order delta_{k-1} before delta_k (ranges may overlap)
        }
    }

    // ---- stage lres (apply delta_k on the fly; same rounding as writer) ----
    const float* rcur = buf_cur + c * NLEN;
    for (int i = t; i < 544; i += 256) {
        int g = qstart + i;
        float x = (g < NLEN) ? rcur[g] : 0.0f;
        int s = g - p;
        if (s >= 0 && s < ATOM_S && g < NLEN) {
            float dval = d_t[((s >> 2) * NATOMS + a) * 4 + (s & 3)];
            x = __fsub_rn(x, __fmul_rn(v, dval));
        }
        lres[i] = x;
    }
    __syncthreads();

    // ---- window compute: sg owns 8 atoms, pg owns 4 positions ----
    int sg = t >> 3, pg = t & 7;
    int base = pg * 4;
    float acc[8][4];
    dot8p(lres, base, (const float4*)d_t + sg * 8, acc);

    float bestv[4] = {-INFINITY, -INFINITY, -INFINITY, -INFINITY};
    int   besta[4] = {0, 0, 0, 0};
#pragma unroll
    for (int aa = 0; aa < 8; ++aa)
#pragma unroll
        for (int j = 0; j < 4; ++j)
            if (acc[aa][j] > bestv[j]) { bestv[j] = acc[aa][j]; besta[j] = sg * 8 + aa; }
#pragma unroll
    for (int j = 0; j < 4; ++j)
        kk[sg * 33 + base + j] = packkey(bestv[j], besta[j], qstart + base + j);
    __syncthreads();
    for (int off = 16; off; off >>= 1) {
        if (sg < off) {
#pragma unroll
            for (int j = 0; j < 4; ++j) {
                unsigned long long o = kk[(sg + off) * 33 + base + j];
                if (o > kk[sg * 33 + base + j]) kk[sg * 33 + base + j] = o;
            }
        }
        __syncthreads();
    }
    // exclusive store of the block's 32 positions (row 0 of kk)
    if (t < 8) {
        unsigned long long* mk = mkey + c * NLEN;
#pragma unroll
        for (int j = 0; j < 4; ++j) {
            int q = qstart + t * 4 + j;
            if (q < w1) mk[q] = kk[t * 4 + j];
        }
    }

    // ---- scan duty + combined block max -> stepkey[k+1] ----
    unsigned long long myk = 0ull;
    {
        const unsigned long long* mk = mkey + c * NLEN;
        int q0 = r * 1024;
#pragma unroll
        for (int i2 = 0; i2 < 4; ++i2) {
            int q = q0 + i2 * 256 + t;
            if (q < w0 || q >= w1) {
                unsigned long long z = mk[q];
                if (z > myk) myk = z;
            }
        }
    }
    if (t < 32) {
        int q = qstart + t;
        if (q < w1) {
            unsigned long long z = kk[t];
            if (z > myk) myk = z;
        }
    }
    kred[t] = myk;
    __syncthreads();
    for (int off = 128; off; off >>= 1) {
        if (t < off) { if (kred[t + off] > kred[t]) kred[t] = kred[t + off]; }
        __syncthreads();
    }
    if (t == 0) atomicMax(&stepkey[(k + 1) * NCHAN + c], kred[0]);
}

// ---------- final loss from stepkey (one block, 256 threads) ----------
__global__ __launch_bounds__(256) void loss_kernel(const unsigned long long* __restrict__ stepkey,
                                                   float* __restrict__ out) {
    int t = threadIdx.x;
    __shared__ int   lsa[NSEL], lsp[NSEL];
    __shared__ float lsv[NSEL];
    __shared__ double red[256];
    __shared__ double smx;

    if (t < NSEL) {
        int c = t >> 4, k = t & 15;            // sel index = c*NSTEPS + k
        unsigned long long key = stepkey[k * NCHAN + c];
        lsa[t] = 255 - (int)((key >> 15) & 255);
        lsp[t] = (NLEN - 1) - (int)(key & 32767);
        lsv[t] = unord32((unsigned int)(key >> 23));
    }
    __syncthreads();

    int myc = (t < NSEL) ? (t >> 4) : -1;
    int mya = (t < NSEL) ? lsa[t] : -1;
    int myp = (t < NSEL) ? lsp[t] : -1;

    // per-(c,a,p) dedup
    int fullowner = t;
    double fullsum = 0.0;
    if (t < NSEL) {
        for (int j = 0; j < NSEL; ++j) {
            if ((j >> 4) == myc && lsa[j] == mya && lsp[j] == myp) {
                if (j < fullowner) fullowner = j;
                fullsum += (double)lsv[j];
            }
        }
    }
    red[t] = (t < NSEL && fullowner == t) ? fullsum : 0.0;
    __syncthreads();
    for (int off = 128; off; off >>= 1) {
        if (t < off) red[t] = fmax(red[t], red[t + off]);
        __syncthreads();
    }
    if (t == 0) smx = red[0];
    __syncthreads();
    double mx = smx;

    // per-(b,a,p) group across r/t halves
    int gowner = t;
    double rv = 0.0, tv = 0.0;
    if (t < NSEL) {
        int myb = myc & 3;
        for (int j = 0; j < NSEL; ++j) {
            int jc = j >> 4;
            if ((jc & 3) == myb && lsa[j] == mya && lsp[j] == myp) {
                if (j < gowner) gowner = j;
                if (jc < 4) rv += (double)lsv[j]; else tv += (double)lsv[j];
            }
        }
    }

    const double EPS = 1e-12;
    double bg_term = -log1p(-EPS);

    double extra = 0.0;
    if (t < NSEL && gowner == t) {
        double r = rv / mx, tt = tv / mx;
        double rc = r;
        if (rc < EPS) rc = EPS;
        if (rc > 1.0) rc = 1.0;
        double lr = log(rc);  if (lr < -100.0) lr = -100.0;
        double l1 = (rc >= 1.0) ? -100.0 : log1p(-rc);
        if (l1 < -100.0) l1 = -100.0;
        double term = -(tt * lr + (1.0 - tt) * l1);
        extra = term - bg_term;
    }

    red[t] = extra;
    __syncthreads();
    for (int off = 128; off; off >>= 1) {
        if (t < off) red[t] += red[t + off];
        __syncthreads();
    }
    if (t == 0) {
        const double count = 33554432.0;  // 4 * 256 * 32768
        double total = count * bg_term + red[0];
        out[0] = (float)(total / count);
    }
}

// ---------- launch ----------
extern "C" void kernel_launch(void* const* d_in, const int* in_sizes, int n_in,
                              void* d_out, int out_size, void* d_ws, size_t ws_size,
                              hipStream_t stream) {
    const float* recon  = (const float*)d_in[0];
    const float* target = (const float*)d_in[1];
    const float* d      = (const float*)d_in[2];
    char* ws = (char*)d_ws;
    float* d_t                    = (float*)(ws);                        // 512 KB
    float* res0                   = (float*)(ws + 524288);               // 1 MB
    float* res1                   = (float*)(ws + 1572864);              // 1 MB
    unsigned long long* mkey      = (unsigned long long*)(ws + 2621440); // 2 MB
    unsigned long long* stepkey   = (unsigned long long*)(ws + 4718592); // 1 KB
    float* out = (float*)d_out;

    hipLaunchKernelGGL(prep_kernel, dim3(NATOMS + 33), dim3(256), 0, stream,
                       recon, target, d, d_t, res0, res1, mkey, stepkey);
    hipLaunchKernelGGL(init_conv, dim3(32, NCHAN, 8), dim3(256), 0, stream,
                       res0, d_t, mkey, stepkey);
    for (int k = 0; k < NSTEPS - 1; ++k) {
        float* cur  = (k & 1) ? res1 : res0;
        float* next = (k & 1) ? res0 : res1;
        hipLaunchKernelGGL(step_kernel, dim3(256), dim3(256), 0, stream,
                           cur, next, d_t, mkey, stepkey, k);
    }
    hipLaunchKernelGGL(loss_kernel, dim3(1), dim3(256), 0, stream,
                       stepkey, out);
}